// Round 6
// baseline (133.292 us; speedup 1.0000x reference)
//
#include <hip/hip_runtime.h>
#include <hip/hip_bf16.h>

// Problem constants (from reference)
#define B_GRAPHS 16384
#define NODES_PER_G 50
#define REPR 128          // (1+L)*EMB
#define PFEAT 1280
#define FEAT 200
#define EMB 32
#define P_ROWS 2000
#define D_ROWS 10000

#define NPF (P_ROWS / 8)            // 250 protein-fuse blocks
#define NDF (D_ROWS / 8)            // 1250 drug-fuse blocks
#define NFUSE (NPF + NDF)           // 1500
#define NPOOL (B_GRAPHS / 4)        // 4096 pool blocks (1 graph per wave, 4/block)
#define NTOT (NPOOL + NFUSE)        // 5596

// ws layout (floats): [0 .. 2*P_ROWS) fuse1-dot [P][2];
//                     [2*P_ROWS ..) fuse2-dot [D][2]

// ---------------------------------------------------------------------------
// Merged kernel, Bresenham-interleaved roles (proven R5). Pool path rebuilt:
// ONE WAVE PER GRAPH -> each wave-load is one contiguous 1 KB segment
// (64 lanes x float4 covering two full 128-float rows), 25 loads/graph,
// 4 independent accumulators, fully unrolled.
//   lane l: row = it*2 + (l>>5), float4-col = l&31.
//   it=0 gives head row (lanes<32) / tail row (lanes>=32).
// ---------------------------------------------------------------------------
__global__ __launch_bounds__(256, 8) void merged_kernel(
    const float* __restrict__ nr,        // node_repr [N][128]
    const float* __restrict__ profeat,   // [P][1280]
    const float* __restrict__ drugfeat,  // [D][200]
    const float* __restrict__ W1p,       // [1280][32]
    const float* __restrict__ b1p,       // [32]
    const float* __restrict__ W2p,       // [32][32]
    const float* __restrict__ W1,        // [200][32]
    const float* __restrict__ b1,        // [32]
    const float* __restrict__ W2,        // [32][32]
    const float* __restrict__ fcW,       // [448][2]
    const float* __restrict__ b2p,       // [32]
    const float* __restrict__ b2,        // [32]
    float*       __restrict__ f1out,     // [P][2]
    float*       __restrict__ f2out,     // [D][2]
    float*       __restrict__ out)       // [B][2] (partial)
{
    const int bid  = blockIdx.x;
    const int Fb  = (int)(((long)bid * NFUSE) / NTOT);
    const int Fb1 = (int)(((long)(bid + 1) * NFUSE) / NTOT);

    if (Fb1 == Fb) {
        // ---------------- graph pooling (pure stream, 1 wave = 1 graph) ----
        const int wid = threadIdx.x >> 6;        // wave in block: 0..3
        const int l   = threadIdx.x & 63;        // lane 0..63
        const int col = l & 31;                  // float4-column within row
        const int g   = (bid - Fb) * 4 + wid;

        const float4* nr4 = (const float4*)nr;
        const long base4 = (long)g * (NODES_PER_G * REPR / 4);  // g*1600

        float4 sp = nr4[base4 + l];              // head (l<32) or tail (l>=32)
        float4 a0, a1, a2, a3;
        a0 = sp;
        a1.x = a1.y = a1.z = a1.w = 0.f;
        a2.x = a2.y = a2.z = a2.w = 0.f;
        a3.x = a3.y = a3.z = a3.w = 0.f;
        #pragma unroll
        for (int it = 1; it <= 24; it += 4) {    // its 1..24 -> rows 2..49
            float4 f0 = nr4[base4 + (it + 0) * 64 + l];
            float4 f1 = nr4[base4 + (it + 1) * 64 + l];
            float4 f2 = nr4[base4 + (it + 2) * 64 + l];
            float4 f3 = nr4[base4 + (it + 3) * 64 + l];
            a0.x += f0.x; a0.y += f0.y; a0.z += f0.z; a0.w += f0.w;
            a1.x += f1.x; a1.y += f1.y; a1.z += f1.z; a1.w += f1.w;
            a2.x += f2.x; a2.y += f2.y; a2.z += f2.z; a2.w += f2.w;
            a3.x += f3.x; a3.y += f3.y; a3.z += f3.z; a3.w += f3.w;
        }
        float4 pool;
        pool.x = (a0.x + a1.x) + (a2.x + a3.x);
        pool.y = (a0.y + a1.y) + (a2.y + a3.y);
        pool.z = (a0.z + a1.z) + (a2.z + a3.z);
        pool.w = (a0.w + a1.w) + (a2.w + a3.w);

        const float4* fcW4 = (const float4*)fcW;
        float4 wg0 = fcW4[col * 2 + 0], wg1 = fcW4[col * 2 + 1];
        float4 wsp0, wsp1;
        float2 fwb;
        float bw;
        if (l < 32) {   // head half: wh slice + b2p bias term
            wsp0 = fcW4[64 + col * 2 + 0];
            wsp1 = fcW4[64 + col * 2 + 1];
            fwb  = *(const float2*)(fcW + (384 + col) * 2);
            bw   = b2p[col];
        } else {        // tail half: wt slice + b2 bias term
            wsp0 = fcW4[128 + col * 2 + 0];
            wsp1 = fcW4[128 + col * 2 + 1];
            fwb  = *(const float2*)(fcW + (416 + col) * 2);
            bw   = b2[col];
        }

        const float inv50 = 1.0f / (float)NODES_PER_G;
        float p0 = inv50 * (pool.x * wg0.x + pool.y * wg0.z + pool.z * wg1.x + pool.w * wg1.z)
                 + sp.x * wsp0.x + sp.y * wsp0.z + sp.z * wsp1.x + sp.w * wsp1.z
                 + bw * fwb.x;
        float p1 = inv50 * (pool.x * wg0.y + pool.y * wg0.w + pool.z * wg1.y + pool.w * wg1.w)
                 + sp.x * wsp0.y + sp.y * wsp0.w + sp.z * wsp1.y + sp.w * wsp1.w
                 + bw * fwb.y;

        for (int m = 32; m >= 1; m >>= 1) {
            p0 += __shfl_xor(p0, m, 64);
            p1 += __shfl_xor(p1, m, 64);
        }
        if (l == 0) {
            out[g * 2 + 0] = p0;   // partial: fuse dots + fc_b added by finalize
            out[g * 2 + 1] = p1;
        }
    } else if (Fb < NPF) {
        // ---------------- protein fuse ---------------- [R3 verbatim]
        const int grp  = threadIdx.x >> 5;
        const int lane = threadIdx.x & 31;
        const int p = Fb * 8 + grp;
        float m0 = 0.f, m1 = 0.f;
        #pragma unroll
        for (int k = 0; k < 32; ++k) {
            float w = W2p[lane * 32 + k];
            float2 fw = *(const float2*)(fcW + (384 + k) * 2);
            m0 = fmaf(w, fw.x, m0);
            m1 = fmaf(w, fw.y, m1);
        }
        const float4* pf4 = (const float4*)(profeat + (long)p * PFEAT);
        float a0 = 0.f, a1 = 0.f, a2 = 0.f, a3 = 0.f;
        #pragma unroll 4
        for (int q = 0; q < PFEAT / 4; q += 4) {
            float4 f0 = pf4[q], f1 = pf4[q + 1], f2 = pf4[q + 2], f3 = pf4[q + 3];
            int k = q * 4;
            a0 = fmaf(f0.x, W1p[(k + 0) * 32 + lane], a0);
            a0 = fmaf(f0.y, W1p[(k + 1) * 32 + lane], a0);
            a0 = fmaf(f0.z, W1p[(k + 2) * 32 + lane], a0);
            a0 = fmaf(f0.w, W1p[(k + 3) * 32 + lane], a0);
            a1 = fmaf(f1.x, W1p[(k + 4) * 32 + lane], a1);
            a1 = fmaf(f1.y, W1p[(k + 5) * 32 + lane], a1);
            a1 = fmaf(f1.z, W1p[(k + 6) * 32 + lane], a1);
            a1 = fmaf(f1.w, W1p[(k + 7) * 32 + lane], a1);
            a2 = fmaf(f2.x, W1p[(k + 8) * 32 + lane], a2);
            a2 = fmaf(f2.y, W1p[(k + 9) * 32 + lane], a2);
            a2 = fmaf(f2.z, W1p[(k + 10) * 32 + lane], a2);
            a2 = fmaf(f2.w, W1p[(k + 11) * 32 + lane], a2);
            a3 = fmaf(f3.x, W1p[(k + 12) * 32 + lane], a3);
            a3 = fmaf(f3.y, W1p[(k + 13) * 32 + lane], a3);
            a3 = fmaf(f3.z, W1p[(k + 14) * 32 + lane], a3);
            a3 = fmaf(f3.w, W1p[(k + 15) * 32 + lane], a3);
        }
        float h = fmaxf((a0 + a1) + (a2 + a3) + b1p[lane], 0.f);
        float p0 = h * m0, p1 = h * m1;
        for (int m = 16; m >= 1; m >>= 1) {
            p0 += __shfl_xor(p0, m, 32);
            p1 += __shfl_xor(p1, m, 32);
        }
        if (lane == 0) {
            f1out[p * 2 + 0] = p0;
            f1out[p * 2 + 1] = p1;
        }
    } else {
        // ---------------- drug fuse ---------------- [R3 verbatim]
        const int grp  = threadIdx.x >> 5;
        const int lane = threadIdx.x & 31;
        const int d = (Fb - NPF) * 8 + grp;
        float m0 = 0.f, m1 = 0.f;
        #pragma unroll
        for (int k = 0; k < 32; ++k) {
            float w = W2[lane * 32 + k];
            float2 fw = *(const float2*)(fcW + (416 + k) * 2);
            m0 = fmaf(w, fw.x, m0);
            m1 = fmaf(w, fw.y, m1);
        }
        const float4* df4 = (const float4*)(drugfeat + (long)d * FEAT);
        float a0 = 0.f, a1 = 0.f;
        #pragma unroll 5
        for (int q = 0; q < FEAT / 4; q += 2) {
            float4 f0 = df4[q], f1 = df4[q + 1];
            int k = q * 4;
            a0 = fmaf(f0.x, W1[(k + 0) * 32 + lane], a0);
            a0 = fmaf(f0.y, W1[(k + 1) * 32 + lane], a0);
            a0 = fmaf(f0.z, W1[(k + 2) * 32 + lane], a0);
            a0 = fmaf(f0.w, W1[(k + 3) * 32 + lane], a0);
            a1 = fmaf(f1.x, W1[(k + 4) * 32 + lane], a1);
            a1 = fmaf(f1.y, W1[(k + 5) * 32 + lane], a1);
            a1 = fmaf(f1.z, W1[(k + 6) * 32 + lane], a1);
            a1 = fmaf(f1.w, W1[(k + 7) * 32 + lane], a1);
        }
        float h = fmaxf(a0 + a1 + b1[lane], 0.f);
        float p0 = h * m0, p1 = h * m1;
        for (int m = 16; m >= 1; m >>= 1) {
            p0 += __shfl_xor(p0, m, 32);
            p1 += __shfl_xor(p1, m, 32);
        }
        if (lane == 0) {
            f2out[d * 2 + 0] = p0;
            f2out[d * 2 + 1] = p1;
        }
    }
}

// ---------------------------------------------------------------------------
// Finalize: one thread per graph. Dedup-table gathers + constant bias.
// ---------------------------------------------------------------------------
__global__ __launch_bounds__(256) void finalize_kernel(
    const int*   __restrict__ head_ids,  // [B]
    const int*   __restrict__ tail_ids,  // [B]
    const int*   __restrict__ node_idx,  // [N]
    const int*   __restrict__ proind,    // [I]
    const int*   __restrict__ drugind,   // [I]
    const float* __restrict__ f1out,     // [P][2]
    const float* __restrict__ f2out,     // [D][2]
    const float* __restrict__ fcb,       // [2]
    float*       __restrict__ out)       // [B][2]
{
    const int g = blockIdx.x * 256 + threadIdx.x;
    if (g >= B_GRAPHS) return;
    const int prow = proind[node_idx[head_ids[g]]];
    const int drow = drugind[node_idx[tail_ids[g]]];
    const float2 f1v = *(const float2*)(f1out + prow * 2);
    const float2 f2v = *(const float2*)(f2out + drow * 2);
    float2 o = *(float2*)(out + g * 2);
    o.x += f1v.x + f2v.x + fcb[0];
    o.y += f1v.y + f2v.y + fcb[1];
    *(float2*)(out + g * 2) = o;
}

extern "C" void kernel_launch(void* const* d_in, const int* in_sizes, int n_in,
                              void* d_out, int out_size, void* d_ws, size_t ws_size,
                              hipStream_t stream) {
    const float* node_repr = (const float*)d_in[0];
    const float* profeat   = (const float*)d_in[1];
    const float* drugfeat  = (const float*)d_in[2];
    const float* W1p       = (const float*)d_in[3];
    const float* b1p       = (const float*)d_in[4];
    const float* W2p       = (const float*)d_in[5];
    const float* b2p       = (const float*)d_in[6];
    const float* W1        = (const float*)d_in[7];
    const float* b1        = (const float*)d_in[8];
    const float* W2        = (const float*)d_in[9];
    const float* b2        = (const float*)d_in[10];
    const float* fc_W      = (const float*)d_in[11];
    const float* fc_b      = (const float*)d_in[12];
    // d_in[13] = graph_ids (unused: blocks are contiguous, 50 nodes each)
    const int* head_ids    = (const int*)d_in[14];
    const int* tail_ids    = (const int*)d_in[15];
    const int* node_idx    = (const int*)d_in[16];
    const int* proind      = (const int*)d_in[17];
    const int* drugind     = (const int*)d_in[18];

    float* f1out = (float*)d_ws;                 // 2000*2 floats
    float* f2out = (float*)d_ws + 2 * P_ROWS;    // 10000*2 floats
    float* out   = (float*)d_out;

    hipLaunchKernelGGL(merged_kernel, dim3(NTOT), dim3(256), 0, stream,
                       node_repr, profeat, drugfeat, W1p, b1p, W2p, W1, b1, W2,
                       fc_W, b2p, b2, f1out, f2out, out);

    hipLaunchKernelGGL(finalize_kernel, dim3(B_GRAPHS / 256), dim3(256), 0, stream,
                       head_ids, tail_ids, node_idx, proind, drugind,
                       f1out, f2out, fc_b, out);
}

// Round 7
// 114.549 us; speedup vs baseline: 1.1636x; 1.1636x over previous
//
#include <hip/hip_runtime.h>
#include <hip/hip_bf16.h>

// Problem constants (from reference)
#define B_GRAPHS 16384
#define NODES_PER_G 50
#define REPR 128          // (1+L)*EMB
#define PFEAT 1280
#define FEAT 200
#define EMB 32
#define P_ROWS 2000
#define D_ROWS 10000

#define NPF (P_ROWS / 8)            // 250 protein-fuse blocks
#define NDF (D_ROWS / 8)            // 1250 drug-fuse blocks
#define NFUSE (NPF + NDF)           // 1500
#define NPOOL (B_GRAPHS / 4)        // 4096 pool blocks (1 graph per wave, 4/block)
#define NTOT (NPOOL + NFUSE)        // 5596

// ws layout (floats): [0 .. 2*P_ROWS) fuse1-dot [P][2];
//                     [2*P_ROWS ..) fuse2-dot [D][2]

// ---------------------------------------------------------------------------
// Merged kernel, Bresenham-interleaved roles (proven R5). Pool path:
// ONE WAVE PER GRAPH -> each wave-load is one contiguous 1 KB segment
// (64 lanes x float4 = two full 128-float rows), 25 loads/graph.
// VGPR-budgeted: 2 loads/iter, unroll 4 -> 8 loads in flight (~32 VGPR of
// data), total ~55 VGPR -> 8 waves/SIMD occupancy retained. NO launch_bounds
// min-waves cap (R6's (256,8) capped VGPR at 64 and strangled MLP).
// ---------------------------------------------------------------------------
__global__ __launch_bounds__(256) void merged_kernel(
    const float* __restrict__ nr,        // node_repr [N][128]
    const float* __restrict__ profeat,   // [P][1280]
    const float* __restrict__ drugfeat,  // [D][200]
    const float* __restrict__ W1p,       // [1280][32]
    const float* __restrict__ b1p,       // [32]
    const float* __restrict__ W2p,       // [32][32]
    const float* __restrict__ W1,        // [200][32]
    const float* __restrict__ b1,        // [32]
    const float* __restrict__ W2,        // [32][32]
    const float* __restrict__ fcW,       // [448][2]
    const float* __restrict__ b2p,       // [32]
    const float* __restrict__ b2,        // [32]
    float*       __restrict__ f1out,     // [P][2]
    float*       __restrict__ f2out,     // [D][2]
    float*       __restrict__ out)       // [B][2] (partial)
{
    const int bid  = blockIdx.x;
    const int Fb  = (int)(((long)bid * NFUSE) / NTOT);
    const int Fb1 = (int)(((long)(bid + 1) * NFUSE) / NTOT);

    if (Fb1 == Fb) {
        // ---------------- graph pooling (pure stream, 1 wave = 1 graph) ----
        const int wid = threadIdx.x >> 6;        // wave in block: 0..3
        const int l   = threadIdx.x & 63;        // lane 0..63
        const int col = l & 31;                  // float4-column within row
        const int g   = (bid - Fb) * 4 + wid;

        const float4* nr4 = (const float4*)nr;
        const long base4 = (long)g * (NODES_PER_G * REPR / 4);  // g*1600

        float4 sp = nr4[base4 + l];              // head (l<32) or tail (l>=32)
        float4 a0, a1;
        a0 = sp;
        a1.x = a1.y = a1.z = a1.w = 0.f;
        #pragma unroll 4
        for (int it = 1; it <= 24; it += 2) {    // its 1..24 -> rows 2..49
            float4 f0 = nr4[base4 + (it + 0) * 64 + l];
            float4 f1 = nr4[base4 + (it + 1) * 64 + l];
            a0.x += f0.x; a0.y += f0.y; a0.z += f0.z; a0.w += f0.w;
            a1.x += f1.x; a1.y += f1.y; a1.z += f1.z; a1.w += f1.w;
        }
        float4 pool;
        pool.x = a0.x + a1.x;
        pool.y = a0.y + a1.y;
        pool.z = a0.z + a1.z;
        pool.w = a0.w + a1.w;

        const float4* fcW4 = (const float4*)fcW;
        float4 wg0 = fcW4[col * 2 + 0], wg1 = fcW4[col * 2 + 1];
        float4 wsp0, wsp1;
        float2 fwb;
        float bw;
        if (l < 32) {   // head half: wh slice + b2p bias term
            wsp0 = fcW4[64 + col * 2 + 0];
            wsp1 = fcW4[64 + col * 2 + 1];
            fwb  = *(const float2*)(fcW + (384 + col) * 2);
            bw   = b2p[col];
        } else {        // tail half: wt slice + b2 bias term
            wsp0 = fcW4[128 + col * 2 + 0];
            wsp1 = fcW4[128 + col * 2 + 1];
            fwb  = *(const float2*)(fcW + (416 + col) * 2);
            bw   = b2[col];
        }

        const float inv50 = 1.0f / (float)NODES_PER_G;
        float p0 = inv50 * (pool.x * wg0.x + pool.y * wg0.z + pool.z * wg1.x + pool.w * wg1.z)
                 + sp.x * wsp0.x + sp.y * wsp0.z + sp.z * wsp1.x + sp.w * wsp1.z
                 + bw * fwb.x;
        float p1 = inv50 * (pool.x * wg0.y + pool.y * wg0.w + pool.z * wg1.y + pool.w * wg1.w)
                 + sp.x * wsp0.y + sp.y * wsp0.w + sp.z * wsp1.y + sp.w * wsp1.w
                 + bw * fwb.y;

        for (int m = 32; m >= 1; m >>= 1) {
            p0 += __shfl_xor(p0, m, 64);
            p1 += __shfl_xor(p1, m, 64);
        }
        if (l == 0) {
            out[g * 2 + 0] = p0;   // partial: fuse dots + fc_b added by finalize
            out[g * 2 + 1] = p1;
        }
    } else if (Fb < NPF) {
        // ---------------- protein fuse ---------------- [R3 verbatim]
        const int grp  = threadIdx.x >> 5;
        const int lane = threadIdx.x & 31;
        const int p = Fb * 8 + grp;
        float m0 = 0.f, m1 = 0.f;
        #pragma unroll
        for (int k = 0; k < 32; ++k) {
            float w = W2p[lane * 32 + k];
            float2 fw = *(const float2*)(fcW + (384 + k) * 2);
            m0 = fmaf(w, fw.x, m0);
            m1 = fmaf(w, fw.y, m1);
        }
        const float4* pf4 = (const float4*)(profeat + (long)p * PFEAT);
        float a0 = 0.f, a1 = 0.f, a2 = 0.f, a3 = 0.f;
        #pragma unroll 4
        for (int q = 0; q < PFEAT / 4; q += 4) {
            float4 f0 = pf4[q], f1 = pf4[q + 1], f2 = pf4[q + 2], f3 = pf4[q + 3];
            int k = q * 4;
            a0 = fmaf(f0.x, W1p[(k + 0) * 32 + lane], a0);
            a0 = fmaf(f0.y, W1p[(k + 1) * 32 + lane], a0);
            a0 = fmaf(f0.z, W1p[(k + 2) * 32 + lane], a0);
            a0 = fmaf(f0.w, W1p[(k + 3) * 32 + lane], a0);
            a1 = fmaf(f1.x, W1p[(k + 4) * 32 + lane], a1);
            a1 = fmaf(f1.y, W1p[(k + 5) * 32 + lane], a1);
            a1 = fmaf(f1.z, W1p[(k + 6) * 32 + lane], a1);
            a1 = fmaf(f1.w, W1p[(k + 7) * 32 + lane], a1);
            a2 = fmaf(f2.x, W1p[(k + 8) * 32 + lane], a2);
            a2 = fmaf(f2.y, W1p[(k + 9) * 32 + lane], a2);
            a2 = fmaf(f2.z, W1p[(k + 10) * 32 + lane], a2);
            a2 = fmaf(f2.w, W1p[(k + 11) * 32 + lane], a2);
            a3 = fmaf(f3.x, W1p[(k + 12) * 32 + lane], a3);
            a3 = fmaf(f3.y, W1p[(k + 13) * 32 + lane], a3);
            a3 = fmaf(f3.z, W1p[(k + 14) * 32 + lane], a3);
            a3 = fmaf(f3.w, W1p[(k + 15) * 32 + lane], a3);
        }
        float h = fmaxf((a0 + a1) + (a2 + a3) + b1p[lane], 0.f);
        float p0 = h * m0, p1 = h * m1;
        for (int m = 16; m >= 1; m >>= 1) {
            p0 += __shfl_xor(p0, m, 32);
            p1 += __shfl_xor(p1, m, 32);
        }
        if (lane == 0) {
            f1out[p * 2 + 0] = p0;
            f1out[p * 2 + 1] = p1;
        }
    } else {
        // ---------------- drug fuse ---------------- [R3 verbatim]
        const int grp  = threadIdx.x >> 5;
        const int lane = threadIdx.x & 31;
        const int d = (Fb - NPF) * 8 + grp;
        float m0 = 0.f, m1 = 0.f;
        #pragma unroll
        for (int k = 0; k < 32; ++k) {
            float w = W2[lane * 32 + k];
            float2 fw = *(const float2*)(fcW + (416 + k) * 2);
            m0 = fmaf(w, fw.x, m0);
            m1 = fmaf(w, fw.y, m1);
        }
        const float4* df4 = (const float4*)(drugfeat + (long)d * FEAT);
        float a0 = 0.f, a1 = 0.f;
        #pragma unroll 5
        for (int q = 0; q < FEAT / 4; q += 2) {
            float4 f0 = df4[q], f1 = df4[q + 1];
            int k = q * 4;
            a0 = fmaf(f0.x, W1[(k + 0) * 32 + lane], a0);
            a0 = fmaf(f0.y, W1[(k + 1) * 32 + lane], a0);
            a0 = fmaf(f0.z, W1[(k + 2) * 32 + lane], a0);
            a0 = fmaf(f0.w, W1[(k + 3) * 32 + lane], a0);
            a1 = fmaf(f1.x, W1[(k + 4) * 32 + lane], a1);
            a1 = fmaf(f1.y, W1[(k + 5) * 32 + lane], a1);
            a1 = fmaf(f1.z, W1[(k + 6) * 32 + lane], a1);
            a1 = fmaf(f1.w, W1[(k + 7) * 32 + lane], a1);
        }
        float h = fmaxf(a0 + a1 + b1[lane], 0.f);
        float p0 = h * m0, p1 = h * m1;
        for (int m = 16; m >= 1; m >>= 1) {
            p0 += __shfl_xor(p0, m, 32);
            p1 += __shfl_xor(p1, m, 32);
        }
        if (lane == 0) {
            f2out[d * 2 + 0] = p0;
            f2out[d * 2 + 1] = p1;
        }
    }
}

// ---------------------------------------------------------------------------
// Finalize: one thread per graph. Dedup-table gathers + constant bias.
// ---------------------------------------------------------------------------
__global__ __launch_bounds__(256) void finalize_kernel(
    const int*   __restrict__ head_ids,  // [B]
    const int*   __restrict__ tail_ids,  // [B]
    const int*   __restrict__ node_idx,  // [N]
    const int*   __restrict__ proind,    // [I]
    const int*   __restrict__ drugind,   // [I]
    const float* __restrict__ f1out,     // [P][2]
    const float* __restrict__ f2out,     // [D][2]
    const float* __restrict__ fcb,       // [2]
    float*       __restrict__ out)       // [B][2]
{
    const int g = blockIdx.x * 256 + threadIdx.x;
    if (g >= B_GRAPHS) return;
    const int prow = proind[node_idx[head_ids[g]]];
    const int drow = drugind[node_idx[tail_ids[g]]];
    const float2 f1v = *(const float2*)(f1out + prow * 2);
    const float2 f2v = *(const float2*)(f2out + drow * 2);
    float2 o = *(float2*)(out + g * 2);
    o.x += f1v.x + f2v.x + fcb[0];
    o.y += f1v.y + f2v.y + fcb[1];
    *(float2*)(out + g * 2) = o;
}

extern "C" void kernel_launch(void* const* d_in, const int* in_sizes, int n_in,
                              void* d_out, int out_size, void* d_ws, size_t ws_size,
                              hipStream_t stream) {
    const float* node_repr = (const float*)d_in[0];
    const float* profeat   = (const float*)d_in[1];
    const float* drugfeat  = (const float*)d_in[2];
    const float* W1p       = (const float*)d_in[3];
    const float* b1p       = (const float*)d_in[4];
    const float* W2p       = (const float*)d_in[5];
    const float* b2p       = (const float*)d_in[6];
    const float* W1        = (const float*)d_in[7];
    const float* b1        = (const float*)d_in[8];
    const float* W2        = (const float*)d_in[9];
    const float* b2        = (const float*)d_in[10];
    const float* fc_W      = (const float*)d_in[11];
    const float* fc_b      = (const float*)d_in[12];
    // d_in[13] = graph_ids (unused: blocks are contiguous, 50 nodes each)
    const int* head_ids    = (const int*)d_in[14];
    const int* tail_ids    = (const int*)d_in[15];
    const int* node_idx    = (const int*)d_in[16];
    const int* proind      = (const int*)d_in[17];
    const int* drugind     = (const int*)d_in[18];

    float* f1out = (float*)d_ws;                 // 2000*2 floats
    float* f2out = (float*)d_ws + 2 * P_ROWS;    // 10000*2 floats
    float* out   = (float*)d_out;

    hipLaunchKernelGGL(merged_kernel, dim3(NTOT), dim3(256), 0, stream,
                       node_repr, profeat, drugfeat, W1p, b1p, W2p, W1, b1, W2,
                       fc_W, b2p, b2, f1out, f2out, out);

    hipLaunchKernelGGL(finalize_kernel, dim3(B_GRAPHS / 256), dim3(256), 0, stream,
                       head_ids, tail_ids, node_idx, proind, drugind,
                       f1out, f2out, fc_b, out);
}